// Round 6
// baseline (1303.673 us; speedup 1.0000x reference)
//
#include <hip/hip_runtime.h>

#define B_ 16
#define N_ 1024
#define M_ 4096
#define D_ 64
#define NB_ 2                   // batches co-resident per workgroup (R5)
#define SROWS_ (N_ + 63)        // 1087 valid skewed steps per tile
#define SROWSP_ (SROWS_ + 17)   // padded stride (prefetch overrun safety)
#define SPAIR_ 544              // step-pairs per tile
#define TSB_ ((size_t)SPAIR_ * 128)  // dec bytes per tile (69632)
#define BTQ_ 96                 // backtrack window quads (384 cells)
#define BTROWS_ 128             // backtrack window rows (2 per lane)

__device__ __forceinline__ float finf() { return __builtin_inff(); }

__device__ __forceinline__ float wave_shr1(float x) {
  return __int_as_float(__builtin_amdgcn_update_dpp(
      0, __float_as_int(x), 0x138, 0xF, 0xF, false));
}
__device__ __forceinline__ float rdlane(float v, int l) {
  return __int_as_float(__builtin_amdgcn_readlane(__float_as_int(v), l));
}

// ---------------------------------------------------------------------------
__global__ void prep_kernel(const float* __restrict__ x,
                            const float* __restrict__ x_t,
                            float* __restrict__ x2,
                            float* __restrict__ w_ts_out) {
  int id = blockIdx.x * blockDim.x + threadIdx.x;
  const float4* xr = (const float4*)(x + (size_t)id * D_);
  float s = 0.f;
#pragma unroll
  for (int e = 0; e < D_ / 4; ++e) {
    float4 v = xr[e];
    s += v.x * v.x + v.y * v.y + v.z * v.z + v.w * v.w;
  }
  x2[id] = s;
  w_ts_out[id] = x_t[id];
}

// ---------------------------------------------------------------------------
// GEMM v2 (R2): register/LDS-tiled, exact same per-cell arithmetic as v1.
// ---------------------------------------------------------------------------
__global__ __launch_bounds__(256) void gemm_kernel(
    const float* __restrict__ x, const float* __restrict__ y,
    const float* __restrict__ x2, float* __restrict__ Cs, int chunkBase) {
  const int b = blockIdx.z;
  const int tile = blockIdx.x;
  const int t = threadIdx.x;
  const int cg = t & 63;
  const int rg = t >> 6;
  const int ibeg = blockIdx.y * 32;
  float* CsT = Cs + (size_t)(b * 4 + tile) * SROWSP_ * 256;

  __shared__ float4 ylds[16 * 256];  // [e][col], 64KB
  __shared__ float4 xlds[16 * 32];   // [e][row], 8KB
  __shared__ float y2lds[256];

  {
    const int j = chunkBase + tile * 256 + t;
    const float4* yrow = (const float4*)(y + ((size_t)b * M_ + j) * D_);
    float4 yr[16];
#pragma unroll
    for (int e = 0; e < 16; ++e) yr[e] = yrow[e];
    float y2 = 0.f;
#pragma unroll
    for (int e = 0; e < 16; ++e)
      y2 += yr[e].x * yr[e].x + yr[e].y * yr[e].y + yr[e].z * yr[e].z +
            yr[e].w * yr[e].w;
    y2lds[t] = y2;
#pragma unroll
    for (int e = 0; e < 16; ++e) ylds[e * 256 + t] = yr[e];
  }
  if (t < 128) {
    const int row = t >> 2;
    const int part = t & 3;
    const float4* xr = (const float4*)(x + ((size_t)b * N_ + ibeg + row) * D_);
#pragma unroll
    for (int k = 0; k < 4; ++k) {
      const int e = part * 4 + k;
      xlds[e * 32 + row] = xr[e];
    }
  }
  __syncthreads();

  const int r0 = rg * 8;
  float acc[8][4];
#pragma unroll
  for (int r = 0; r < 8; ++r)
#pragma unroll
    for (int c = 0; c < 4; ++c) acc[r][c] = 0.f;

#pragma unroll
  for (int kb = 0; kb < 4; ++kb) {
    float4 yf[4][4];  // [c][ee]
#pragma unroll
    for (int c = 0; c < 4; ++c)
#pragma unroll
      for (int ee = 0; ee < 4; ++ee)
        yf[c][ee] = ylds[(kb * 4 + ee) * 256 + cg + 64 * c];
#pragma unroll
    for (int r = 0; r < 8; ++r) {
      float4 xv[4];
#pragma unroll
      for (int ee = 0; ee < 4; ++ee)
        xv[ee] = xlds[(kb * 4 + ee) * 32 + r0 + r];
#pragma unroll
      for (int ee = 0; ee < 4; ++ee) {
#pragma unroll
        for (int c = 0; c < 4; ++c) {
          acc[r][c] += xv[ee].x * yf[c][ee].x + xv[ee].y * yf[c][ee].y +
                       xv[ee].z * yf[c][ee].z + xv[ee].w * yf[c][ee].w;
        }
      }
    }
  }

#pragma unroll
  for (int r = 0; r < 8; ++r) {
    const int i = ibeg + r0 + r;
    const float xx = x2[b * N_ + i];
#pragma unroll
    for (int c = 0; c < 4; ++c) {
      const int ct = cg + 64 * c;
      const int l = ct >> 2;
      CsT[(size_t)(i + l) * 256 + ct] = xx + y2lds[ct] - 2.f * acc[r][c];
    }
  }
}

// ---------------------------------------------------------------------------
// Systolic DP v5 (R5): NB_=2 batches per 512-thread workgroup -> 2 waves per
// SIMD (was 1). Same-role waves of the two batches share a SIMD and hide each
// other's latency stalls. Per-batch state (ring/cring/prog/red) is disjoint;
// batches couple only at entry/exit __syncthreads. DP recurrence unchanged
// (min3 pk encoding verified bit-exact in R4/R5). 1-deep Cs prefetch,
// 8-step blocks, per-block poll (R2 structure, best measured).
// ---------------------------------------------------------------------------
__global__ __launch_bounds__(512) void dtw_dp(
    const float* __restrict__ Cs, unsigned char* __restrict__ dec,
    const float* __restrict__ carryIn, float* __restrict__ carryOut,
    float* __restrict__ partV, int* __restrict__ partJ,
    int chunk, int hasCarry) {
  const int t = threadIdx.x;
  const int tb = t & 255;        // within-batch tid
  const int G = t >> 8;          // batch slot in this WG
  const int b = blockIdx.x * NB_ + G;
  const int lane = tb & 63;
  const int W = tb >> 6;

  __shared__ float ring[NB_][3][1024];
  __shared__ float cring[NB_][1024];
  __shared__ int prog[NB_][3];
  __shared__ float redV[NB_][4];
  __shared__ int redJ[NB_][4];
  volatile int* vProg = prog[G];

  if (tb < 3) prog[G][tb] = -1;
  const float* cIn = carryIn + b * N_;
  if (hasCarry) ((float4*)cring[G])[tb] = ((const float4*)cIn)[tb];
  __syncthreads();

  const float INF = finf();
  const float* loadP = Cs + (size_t)(b * 4 + W) * SROWSP_ * 256;
  const int tileG = chunk * 4 + W;
  unsigned short* decP =
      (unsigned short*)(dec + (size_t)(b * 16 + tileG) * TSB_) + lane;
  float* carryB = carryOut + b * N_;
  const int jbase = tileG * 256 + lane * 4;

  float4 cc0 = ((const float4*)(loadP + 0 * 256))[lane];
  float4 cc1 = ((const float4*)(loadP + 1 * 256))[lane];
  float4 cc2 = ((const float4*)(loadP + 2 * 256))[lane];
  float4 cc3 = ((const float4*)(loadP + 3 * 256))[lane];
  float4 cc4 = ((const float4*)(loadP + 4 * 256))[lane];
  float4 cc5 = ((const float4*)(loadP + 5 * 256))[lane];
  float4 cc6 = ((const float4*)(loadP + 6 * 256))[lane];
  float4 cc7 = ((const float4*)(loadP + 7 * 256))[lane];
  loadP += 8 * 256;

  float edgeVec = INF, lvPrev = INF;
  float up0 = 0.f, up1 = 0.f, up2 = 0.f, up3 = 0.f;
  float dpp1 = INF, dpp2 = INF;
  float fin0 = INF, fin1 = INF, fin2 = INF, fin3 = INF;
  float ebuf[8];

#define BLOCKHEAD()                                                           \
  {                                                                           \
    if (W > 0) {                                                              \
      if (sb < N_) {                                                          \
        const int tgt = sb + 7;                                               \
        while (vProg[W - 1] < tgt) {}                                         \
        asm volatile("" ::: "memory");                                        \
        lvPrev = rdlane(edgeVec, 7);                                          \
        edgeVec = ring[G][W - 1][(sb + lane) & 1023];                         \
      }                                                                       \
    } else if (hasCarry) {                                                    \
      lvPrev = rdlane(edgeVec, 7);                                            \
      if (sb < N_) edgeVec = cring[G][(sb + lane) & 1023];                    \
    }                                                                         \
  }

#define DPSTEP(KK, CCV, ROW0, FIN)                                            \
  {                                                                           \
    const float lv = rdlane(edgeVec, (KK));                                   \
    const float left = (lane == 0) ? lv : dpp1;                               \
    const float diag = (lane == 0) ? lvPrev : dpp2;                           \
    lvPrev = lv;                                                              \
    float bv0 = fminf(diag, fminf(up0, left));                                \
    unsigned int pk = (diag <= bv0) ? 0u : ((up0 <= bv0) ? 1u : 2u);          \
    if (ROW0) bv0 = (sb + (KK) == lane) ? 0.f : bv0;                          \
    const float D0 = CCV.x + bv0;                                             \
    float bv1 = fminf(up0, fminf(up1, D0));                                   \
    pk |= (up0 <= bv1) ? 0u : ((up1 <= bv1) ? 4u : 8u);                       \
    if (ROW0) bv1 = (sb + (KK) == lane) ? 0.f : bv1;                          \
    const float D1 = CCV.y + bv1;                                             \
    float bv2 = fminf(up1, fminf(up2, D1));                                   \
    pk |= (up1 <= bv2) ? 0u : ((up2 <= bv2) ? 16u : 32u);                     \
    if (ROW0) bv2 = (sb + (KK) == lane) ? 0.f : bv2;                          \
    const float D2 = CCV.z + bv2;                                             \
    float bv3 = fminf(up2, fminf(up3, D2));                                   \
    pk |= (up2 <= bv3) ? 0u : ((up3 <= bv3) ? 64u : 128u);                    \
    if (ROW0) bv3 = (sb + (KK) == lane) ? 0.f : bv3;                          \
    const float D3 = CCV.w + bv3;                                             \
    ebuf[(KK)] = D3;                                                          \
    if ((KK) & 1) {                                                           \
      pk16 |= pk << 8;                                                        \
      decP[((KK) >> 1) * 64] = (unsigned short)pk16;                          \
    } else {                                                                  \
      pk16 = pk;                                                              \
    }                                                                         \
    if (FIN) {                                                                \
      const bool lr = (sb + (KK) == 1023 + lane);                             \
      fin0 = lr ? D0 : fin0; fin1 = lr ? D1 : fin1;                           \
      fin2 = lr ? D2 : fin2; fin3 = lr ? D3 : fin3;                           \
    }                                                                         \
    const float sh = wave_shr1(D3);                                           \
    dpp2 = dpp1; dpp1 = sh;                                                   \
    up0 = D0; up1 = D1; up2 = D2; up3 = D3;                                   \
    CCV = ((const float4*)(loadP + (KK) * 256))[lane];                        \
  }

#define BLOCKEND()                                                            \
  {                                                                           \
    const int r0 = sb - 63;                                                   \
    if (W < 3) {                                                              \
      if (lane == 63 && r0 > -8 && r0 < N_) {                                 \
        _Pragma("unroll") for (int k = 0; k < 8; ++k) {                       \
          const int r = r0 + k;                                               \
          if ((unsigned)r < (unsigned)N_) ring[G][W][r] = ebuf[k];            \
        }                                                                     \
        __builtin_amdgcn_s_waitcnt(0xC07F);                                   \
        vProg[W] = r0 + 7;                                                    \
      }                                                                       \
    } else if (chunk < 3) {                                                   \
      if (lane == 63 && r0 > -8 && r0 < N_) {                                 \
        _Pragma("unroll") for (int k = 0; k < 8; ++k) {                       \
          const int r = r0 + k;                                               \
          if ((unsigned)r < (unsigned)N_) carryB[r] = ebuf[k];                \
        }                                                                     \
      }                                                                       \
    }                                                                         \
    loadP += 8 * 256;                                                         \
    decP += 256;                                                              \
  }

#define STEP8(R0, FN)                                                         \
  DPSTEP(0, cc0, R0, FN) DPSTEP(1, cc1, R0, FN) DPSTEP(2, cc2, R0, FN)        \
  DPSTEP(3, cc3, R0, FN) DPSTEP(4, cc4, R0, FN) DPSTEP(5, cc5, R0, FN)        \
  DPSTEP(6, cc6, R0, FN) DPSTEP(7, cc7, R0, FN)

  int sb = 0;
  for (; sb < 64; sb += 8) {   // prologue: row-0 selects live
    BLOCKHEAD();
    unsigned int pk16;
    STEP8(1, 0)
    BLOCKEND();
  }
  for (; sb < 1016; sb += 8) { // main
    BLOCKHEAD();
    unsigned int pk16;
    STEP8(0, 0)
    BLOCKEND();
  }
  for (; sb < 1088; sb += 8) { // epilogue: fin captures
    BLOCKHEAD();
    unsigned int pk16;
    STEP8(0, 1)
    BLOCKEND();
  }
#undef DPSTEP
#undef STEP8
#undef BLOCKHEAD
#undef BLOCKEND

  float mv = fin0; int mj = jbase;
  if (fin1 < mv) { mv = fin1; mj = jbase + 1; }
  if (fin2 < mv) { mv = fin2; mj = jbase + 2; }
  if (fin3 < mv) { mv = fin3; mj = jbase + 3; }
#pragma unroll
  for (int off = 32; off > 0; off >>= 1) {
    const float ov = __shfl_down(mv, off);
    const int oj = __shfl_down(mj, off);
    if (ov < mv || (ov == mv && oj < mj)) { mv = ov; mj = oj; }
  }
  if (lane == 0) { redV[G][W] = mv; redJ[G][W] = mj; }
  __syncthreads();
  if (tb == 0) {
    float bm = redV[G][0]; int bj = redJ[G][0];
#pragma unroll
    for (int w = 1; w < 4; ++w)
      if (redV[G][w] < bm) { bm = redV[G][w]; bj = redJ[G][w]; }
    partV[b * 4 + chunk] = bm;
    partJ[b * 4 + chunk] = bj;
  }
}

// ---------------------------------------------------------------------------
// Backtrack v3 (R3): 128-row windows, 2 rows decoded per lane. Stage 3 tiles
// x 96 p-rows x 128B = 36KB coalesced into LDS (XOR bank swizzle), decode
// into tab[128][...], serial lane-0 walk up to 128 rows per window.
// ---------------------------------------------------------------------------
__global__ __launch_bounds__(64) void backtrack_kernel(
    const unsigned char* __restrict__ dec, const float* __restrict__ partV,
    const int* __restrict__ partJ, int nch, const float* __restrict__ y_t,
    float* __restrict__ w_vs, float* __restrict__ cost_out) {
  const int b = blockIdx.x;
  const int lane = threadIdx.x;
  __shared__ unsigned int stage[3 * 3072];               // 36 KB
  __shared__ unsigned short tab[BTROWS_][BTQ_ * 4 + 2];  // ~98.8 KB
  __shared__ int st_i, st_j;
  __shared__ int jrow[BTROWS_ + 1];
  const unsigned char* db = dec + (size_t)b * 16 * TSB_;
  const float* yt = y_t + b * M_;
  float* wv = w_vs + b * N_;

  if (lane == 0) {
    float bc = finf(); int bj = 0;
    for (int c = 0; c < nch; ++c) {
      const float v = partV[b * nch + c];
      const int j = partJ[b * nch + c];
      if (v < bc) { bc = v; bj = j; }
    }
    cost_out[b] = bc;
    st_i = N_ - 1;
    st_j = bj;
    wv[N_ - 1] = yt[bj];
  }
  for (;;) {
    __syncthreads();
    const int i = st_i, j = st_j;
    if (i <= 0) break;
    const int qj = j >> 2;
    int qlo = qj - (BTQ_ - 1);
    if (qlo < 0) qlo = 0;
    const int Tbase = qlo >> 6;
    int plo = (i - 127) >> 1;
    if (plo < 0) plo = 0;  // i<=1023 => plo<=448, plo+95<=543=SPAIR_-1

    // --- cooperative coalesced stage: 3 tiles x 96 p-rows x 128B ---
#pragma unroll
    for (int tt = 0; tt < 3; ++tt) {
      int T = Tbase + tt;
      if (T > 15) T = 15;  // duplicate tile 15; never read for that tt
      const uint4* src =
          (const uint4*)(db + (size_t)T * TSB_ + (size_t)plo * 128);
#pragma unroll
      for (int v = 0; v < 12; ++v) {
        const int wb = tt * 12288 + (v * 64 + lane) * 16;
        const int sw = wb ^ (((wb >> 7) & 7) << 4);  // bank swizzle
        *(uint4*)((char*)stage + sw) = src[v * 64 + lane];
      }
    }
    __syncthreads();

    const unsigned char* sb8 = (const unsigned char*)stage;
#pragma unroll
    for (int half = 0; half < 2; ++half) {
      const int r = i - lane - half * 64;
      if (r >= 1) {
        unsigned char wr[BTQ_];
#pragma unroll
        for (int k = 0; k < BTQ_; ++k) {
          const int q = qlo + k;
          const int tt = (q >> 6) - Tbase;
          const int l = q & 63;
          const int s = r + l;
          int idx = tt * 12288 + ((s >> 1) - plo) * 128 + l * 2 + (s & 1);
          idx ^= ((idx >> 7) & 7) << 4;  // matching bank swizzle
          wr[k] = sb8[idx];
        }
        unsigned short run = 0xFFFF;  // stuck sentinel
        const int tr = lane + half * 64;
#pragma unroll
        for (int k = 0; k < BTQ_; ++k) {
          const unsigned int byte = wr[k];
#pragma unroll
          for (int cs = 0; cs < 4; ++cs) {
            const unsigned int code = (byte >> (2 * cs)) & 3u;
            const int c = 4 * k + cs;
            const unsigned short v =
                (code != 2u) ? (unsigned short)((c << 2) | code) : run;
            tab[tr][c] = v;
            run = v;
          }
        }
      }
    }
    __syncthreads();
    if (lane == 0) {
      const int base = qlo << 2;
      int rr = i, cj = j;
      while (rr >= 1 && (i - rr) < BTROWS_) {
        const int l = i - rr;
        const int c = cj - base;
        if (c < 0) break;
        const unsigned short v = tab[l][c];
        if (v == 0xFFFF) { cj = base - 1; break; }
        const int e = v >> 2;
        const int ce = v & 3;
        cj = base + e - (ce == 0 ? 1 : 0);
        --rr;
        jrow[i - rr] = cj;
      }
      st_i = rr;
      st_j = cj;
    }
    __syncthreads();
    const int cnt = i - st_i;
    if (lane < cnt) wv[i - 1 - lane] = yt[jrow[lane + 1]];
    {
      const int l2 = lane + 64;
      if (l2 < cnt) wv[i - 1 - l2] = yt[jrow[l2 + 1]];
    }
  }
}

// ---------------------------------------------------------------------------
extern "C" void kernel_launch(void* const* d_in, const int* in_sizes, int n_in,
                              void* d_out, int out_size, void* d_ws, size_t ws_size,
                              hipStream_t stream) {
  const float* x = (const float*)d_in[0];
  const float* y = (const float*)d_in[1];
  const float* x_t = (const float*)d_in[2];
  const float* y_t = (const float*)d_in[3];

  float* out_cost = (float*)d_out;      // [B_]
  float* out_wts = out_cost + B_;       // [B_][N_]
  float* out_wvs = out_wts + B_ * N_;   // [B_][N_]

  const size_t csBytes = (size_t)B_ * 4 * SROWSP_ * 256 * 4;  // ~72.4 MB
  const size_t decBytes = (size_t)B_ * 16 * TSB_;             // ~17.8 MB
  const size_t x2Bytes = (size_t)B_ * N_ * 4;

  char* ws = (char*)d_ws;
  float* Cs = (float*)ws;
  unsigned char* dec = (unsigned char*)(ws + csBytes);
  float* x2 = (float*)(ws + csBytes + decBytes);
  float* carryA = (float*)(ws + csBytes + decBytes + x2Bytes);
  float* carryB = carryA + B_ * N_;
  float* partV = carryB + B_ * N_;
  int* partJ = (int*)(partV + B_ * 4);

  prep_kernel<<<dim3((B_ * N_) / 256), 256, 0, stream>>>(x, x_t, x2, out_wts);

  float* cbuf[2] = {carryA, carryB};
  for (int c = 0; c < 4; ++c) {
    gemm_kernel<<<dim3(4, N_ / 32, B_), 256, 0, stream>>>(x, y, x2, Cs,
                                                          c * 1024);
    const float* cin = cbuf[(c + 1) & 1];
    float* cout = cbuf[c & 1];
    dtw_dp<<<dim3(B_ / NB_), 256 * NB_, 0, stream>>>(Cs, dec, cin, cout,
                                                     partV, partJ, c,
                                                     c > 0 ? 1 : 0);
  }

  backtrack_kernel<<<dim3(B_), 64, 0, stream>>>(dec, partV, partJ, 4, y_t,
                                                out_wvs, out_cost);
}

// Round 7
// 1011.748 us; speedup vs baseline: 1.2885x; 1.2885x over previous
//
#include <hip/hip_runtime.h>

#define B_ 16
#define N_ 1024
#define M_ 4096
#define D_ 64
#define SROWS_ (N_ + 63)        // 1087 valid skewed steps per tile
#define SROWSP_ (SROWS_ + 17)   // padded stride (prefetch overrun safety)
#define SPAIR_ 544              // step-pairs per tile
#define TSB_ ((size_t)SPAIR_ * 128)  // dec bytes per tile (69632)
#define BTQ_ 96                 // backtrack window quads (384 cells)
#define BTROWS_ 128             // backtrack window rows (2 per lane)
#define GEMM_BLKS_ 2048         // 4 tiles x 32 row-groups x 16 batches

__device__ __forceinline__ float finf() { return __builtin_inff(); }

__device__ __forceinline__ float wave_shr1(float x) {
  return __int_as_float(__builtin_amdgcn_update_dpp(
      0, __float_as_int(x), 0x138, 0xF, 0xF, false));
}
__device__ __forceinline__ float rdlane(float v, int l) {
  return __int_as_float(__builtin_amdgcn_readlane(__float_as_int(v), l));
}

// ---------------------------------------------------------------------------
__global__ void prep_kernel(const float* __restrict__ x,
                            const float* __restrict__ x_t,
                            float* __restrict__ x2,
                            float* __restrict__ w_ts_out) {
  int id = blockIdx.x * blockDim.x + threadIdx.x;
  const float4* xr = (const float4*)(x + (size_t)id * D_);
  float s = 0.f;
#pragma unroll
  for (int e = 0; e < D_ / 4; ++e) {
    float4 v = xr[e];
    s += v.x * v.x + v.y * v.y + v.z * v.z + v.w * v.w;
  }
  x2[id] = s;
  w_ts_out[id] = x_t[id];
}

// ---------------------------------------------------------------------------
// gemm body (shared by prologue kernel and fused kernel). Exact same per-cell
// arithmetic as R2's verified gemm v2 (bit-identical C required).
// ---------------------------------------------------------------------------
__device__ __forceinline__ void gemm_body(
    const float* __restrict__ x, const float* __restrict__ y,
    const float* __restrict__ x2, float* __restrict__ Cs, int chunkBase,
    int b, int tile, int ibeg, int t, char* smem) {
  float4* ylds = (float4*)smem;            // [e][col], 64KB
  float4* xlds = (float4*)(smem + 65536);  // [e][row], 8KB
  float* y2lds = (float*)(smem + 73728);   // 1KB
  const int cg = t & 63;
  const int rg = t >> 6;
  float* CsT = Cs + (size_t)(b * 4 + tile) * SROWSP_ * 256;

  {
    const int j = chunkBase + tile * 256 + t;
    const float4* yrow = (const float4*)(y + ((size_t)b * M_ + j) * D_);
    float4 yr[16];
#pragma unroll
    for (int e = 0; e < 16; ++e) yr[e] = yrow[e];
    float y2 = 0.f;
#pragma unroll
    for (int e = 0; e < 16; ++e)
      y2 += yr[e].x * yr[e].x + yr[e].y * yr[e].y + yr[e].z * yr[e].z +
            yr[e].w * yr[e].w;
    y2lds[t] = y2;
#pragma unroll
    for (int e = 0; e < 16; ++e) ylds[e * 256 + t] = yr[e];
  }
  if (t < 128) {
    const int row = t >> 2;
    const int part = t & 3;
    const float4* xr = (const float4*)(x + ((size_t)b * N_ + ibeg + row) * D_);
#pragma unroll
    for (int k = 0; k < 4; ++k) {
      const int e = part * 4 + k;
      xlds[e * 32 + row] = xr[e];
    }
  }
  __syncthreads();

  const int r0 = rg * 8;
  float acc[8][4];
#pragma unroll
  for (int r = 0; r < 8; ++r)
#pragma unroll
    for (int c = 0; c < 4; ++c) acc[r][c] = 0.f;

#pragma unroll
  for (int kb = 0; kb < 4; ++kb) {
    float4 yf[4][4];  // [c][ee]
#pragma unroll
    for (int c = 0; c < 4; ++c)
#pragma unroll
      for (int ee = 0; ee < 4; ++ee)
        yf[c][ee] = ylds[(kb * 4 + ee) * 256 + cg + 64 * c];
#pragma unroll
    for (int r = 0; r < 8; ++r) {
      float4 xv[4];
#pragma unroll
      for (int ee = 0; ee < 4; ++ee)
        xv[ee] = xlds[(kb * 4 + ee) * 32 + r0 + r];
#pragma unroll
      for (int ee = 0; ee < 4; ++ee) {
#pragma unroll
        for (int c = 0; c < 4; ++c) {
          acc[r][c] += xv[ee].x * yf[c][ee].x + xv[ee].y * yf[c][ee].y +
                       xv[ee].z * yf[c][ee].z + xv[ee].w * yf[c][ee].w;
        }
      }
    }
  }

#pragma unroll
  for (int r = 0; r < 8; ++r) {
    const int i = ibeg + r0 + r;
    const float xx = x2[b * N_ + i];
#pragma unroll
    for (int c = 0; c < 4; ++c) {
      const int ct = cg + 64 * c;
      const int l = ct >> 2;
      CsT[(size_t)(i + l) * 256 + ct] = xx + y2lds[ct] - 2.f * acc[r][c];
    }
  }
}

// ---------------------------------------------------------------------------
// Prologue GEMM (chunk 0 only).
// ---------------------------------------------------------------------------
__global__ __launch_bounds__(256) void gemm_kernel(
    const float* __restrict__ x, const float* __restrict__ y,
    const float* __restrict__ x2, float* __restrict__ Cs, int chunkBase) {
  __shared__ __align__(16) char smem[74752];
  gemm_body(x, y, x2, Cs, chunkBase, blockIdx.z, blockIdx.x, blockIdx.y * 32,
            threadIdx.x, smem);
}

// ---------------------------------------------------------------------------
// Fused kernel (R6): blocks 0..15 run systolic DP for chunk c (reading
// CsRead, written by the PREVIOUS launch); blocks 16.. run the gemm for
// chunk c+1 (writing CsWrite). Launch boundaries provide the ordering.
// Static LDS = 88 KB so no two blocks share a CU (160 KB/CU): DP blocks
// stay isolated at 1 wave/SIMD (R5 showed co-residency slows DP ~15%).
// DP structure = R3 best (1-deep prefetch, 8-step blocks, per-block poll)
// + min3 pk encoding (bit-exact, verified R4/R5).
// ---------------------------------------------------------------------------
__global__ __launch_bounds__(256) void dtw_fused(
    const float* __restrict__ x, const float* __restrict__ y,
    const float* __restrict__ x2, const float* __restrict__ CsRead,
    float* __restrict__ CsWrite, int nextBase,
    unsigned char* __restrict__ dec, const float* __restrict__ carryIn,
    float* __restrict__ carryOut, float* __restrict__ partV,
    int* __restrict__ partJ, int chunk, int hasCarry) {
  __shared__ __align__(16) char smem[90112];  // 88 KB: blocks never co-reside
  const int bid = blockIdx.x;
  const int t = threadIdx.x;

  if (bid >= B_) {  // ---- gemm for chunk+1 ----
    const int gb = bid - B_;
    gemm_body(x, y, x2, CsWrite, nextBase, gb >> 7, gb & 3,
              ((gb >> 2) & 31) * 32, t, smem);
    return;
  }

  // ---- systolic DP for this chunk ----
  float(*ring)[1024] = reinterpret_cast<float(*)[1024]>(smem);  // 12 KB
  float* cring = reinterpret_cast<float*>(smem + 12288);        // 4 KB
  int* prog = reinterpret_cast<int*>(smem + 16384);
  float* redV = reinterpret_cast<float*>(smem + 16400);
  int* redJ = reinterpret_cast<int*>(smem + 16416);
  volatile int* vProg = prog;

  const int b = bid;
  const int lane = t & 63;
  const int W = t >> 6;

  if (t < 3) prog[t] = -1;
  const float* cIn = carryIn + b * N_;
  if (hasCarry) ((float4*)cring)[t] = ((const float4*)cIn)[t];
  __syncthreads();

  const float INF = finf();
  const float* loadP = CsRead + (size_t)(b * 4 + W) * SROWSP_ * 256;
  const int tileG = chunk * 4 + W;
  unsigned short* decP =
      (unsigned short*)(dec + (size_t)(b * 16 + tileG) * TSB_) + lane;
  float* carryB = carryOut + b * N_;
  const int jbase = tileG * 256 + lane * 4;

  float4 cc0 = ((const float4*)(loadP + 0 * 256))[lane];
  float4 cc1 = ((const float4*)(loadP + 1 * 256))[lane];
  float4 cc2 = ((const float4*)(loadP + 2 * 256))[lane];
  float4 cc3 = ((const float4*)(loadP + 3 * 256))[lane];
  float4 cc4 = ((const float4*)(loadP + 4 * 256))[lane];
  float4 cc5 = ((const float4*)(loadP + 5 * 256))[lane];
  float4 cc6 = ((const float4*)(loadP + 6 * 256))[lane];
  float4 cc7 = ((const float4*)(loadP + 7 * 256))[lane];
  loadP += 8 * 256;

  float edgeVec = INF, lvPrev = INF;
  float up0 = 0.f, up1 = 0.f, up2 = 0.f, up3 = 0.f;
  float dpp1 = INF, dpp2 = INF;
  float fin0 = INF, fin1 = INF, fin2 = INF, fin3 = INF;
  float ebuf[8];

#define BLOCKHEAD()                                                           \
  {                                                                           \
    if (W > 0) {                                                              \
      if (sb < N_) {                                                          \
        const int tgt = sb + 7;                                               \
        while (vProg[W - 1] < tgt) {}                                         \
        asm volatile("" ::: "memory");                                        \
        lvPrev = rdlane(edgeVec, 7);                                          \
        edgeVec = ring[W - 1][(sb + lane) & 1023];                            \
      }                                                                       \
    } else if (hasCarry) {                                                    \
      lvPrev = rdlane(edgeVec, 7);                                            \
      if (sb < N_) edgeVec = cring[(sb + lane) & 1023];                       \
    }                                                                         \
  }

#define DPSTEP(KK, CCV, ROW0, FIN)                                            \
  {                                                                           \
    const float lv = rdlane(edgeVec, (KK));                                   \
    const float left = (lane == 0) ? lv : dpp1;                               \
    const float diag = (lane == 0) ? lvPrev : dpp2;                           \
    lvPrev = lv;                                                              \
    float bv0 = fminf(diag, fminf(up0, left));                                \
    unsigned int pk = (diag <= bv0) ? 0u : ((up0 <= bv0) ? 1u : 2u);          \
    if (ROW0) bv0 = (sb + (KK) == lane) ? 0.f : bv0;                          \
    const float D0 = CCV.x + bv0;                                             \
    float bv1 = fminf(up0, fminf(up1, D0));                                   \
    pk |= (up0 <= bv1) ? 0u : ((up1 <= bv1) ? 4u : 8u);                       \
    if (ROW0) bv1 = (sb + (KK) == lane) ? 0.f : bv1;                          \
    const float D1 = CCV.y + bv1;                                             \
    float bv2 = fminf(up1, fminf(up2, D1));                                   \
    pk |= (up1 <= bv2) ? 0u : ((up2 <= bv2) ? 16u : 32u);                     \
    if (ROW0) bv2 = (sb + (KK) == lane) ? 0.f : bv2;                          \
    const float D2 = CCV.z + bv2;                                             \
    float bv3 = fminf(up2, fminf(up3, D2));                                   \
    pk |= (up2 <= bv3) ? 0u : ((up3 <= bv3) ? 64u : 128u);                    \
    if (ROW0) bv3 = (sb + (KK) == lane) ? 0.f : bv3;                          \
    const float D3 = CCV.w + bv3;                                             \
    ebuf[(KK)] = D3;                                                          \
    if ((KK) & 1) {                                                           \
      pk16 |= pk << 8;                                                        \
      decP[((KK) >> 1) * 64] = (unsigned short)pk16;                          \
    } else {                                                                  \
      pk16 = pk;                                                              \
    }                                                                         \
    if (FIN) {                                                                \
      const bool lr = (sb + (KK) == 1023 + lane);                             \
      fin0 = lr ? D0 : fin0; fin1 = lr ? D1 : fin1;                           \
      fin2 = lr ? D2 : fin2; fin3 = lr ? D3 : fin3;                           \
    }                                                                         \
    const float sh = wave_shr1(D3);                                           \
    dpp2 = dpp1; dpp1 = sh;                                                   \
    up0 = D0; up1 = D1; up2 = D2; up3 = D3;                                   \
    CCV = ((const float4*)(loadP + (KK) * 256))[lane];                        \
  }

#define BLOCKEND()                                                            \
  {                                                                           \
    const int r0 = sb - 63;                                                   \
    if (W < 3) {                                                              \
      if (lane == 63 && r0 > -8 && r0 < N_) {                                 \
        _Pragma("unroll") for (int k = 0; k < 8; ++k) {                       \
          const int r = r0 + k;                                               \
          if ((unsigned)r < (unsigned)N_) ring[W][r] = ebuf[k];               \
        }                                                                     \
        __builtin_amdgcn_s_waitcnt(0xC07F);                                   \
        vProg[W] = r0 + 7;                                                    \
      }                                                                       \
    } else if (chunk < 3) {                                                   \
      if (lane == 63 && r0 > -8 && r0 < N_) {                                 \
        _Pragma("unroll") for (int k = 0; k < 8; ++k) {                       \
          const int r = r0 + k;                                               \
          if ((unsigned)r < (unsigned)N_) carryB[r] = ebuf[k];                \
        }                                                                     \
      }                                                                       \
    }                                                                         \
    loadP += 8 * 256;                                                         \
    decP += 256;                                                              \
  }

#define STEP8(R0, FN)                                                         \
  DPSTEP(0, cc0, R0, FN) DPSTEP(1, cc1, R0, FN) DPSTEP(2, cc2, R0, FN)        \
  DPSTEP(3, cc3, R0, FN) DPSTEP(4, cc4, R0, FN) DPSTEP(5, cc5, R0, FN)        \
  DPSTEP(6, cc6, R0, FN) DPSTEP(7, cc7, R0, FN)

  int sb = 0;
  for (; sb < 64; sb += 8) {   // prologue: row-0 selects live
    BLOCKHEAD();
    unsigned int pk16;
    STEP8(1, 0)
    BLOCKEND();
  }
  for (; sb < 1016; sb += 8) { // main
    BLOCKHEAD();
    unsigned int pk16;
    STEP8(0, 0)
    BLOCKEND();
  }
  for (; sb < 1088; sb += 8) { // epilogue: fin captures
    BLOCKHEAD();
    unsigned int pk16;
    STEP8(0, 1)
    BLOCKEND();
  }
#undef DPSTEP
#undef STEP8
#undef BLOCKHEAD
#undef BLOCKEND

  float mv = fin0; int mj = jbase;
  if (fin1 < mv) { mv = fin1; mj = jbase + 1; }
  if (fin2 < mv) { mv = fin2; mj = jbase + 2; }
  if (fin3 < mv) { mv = fin3; mj = jbase + 3; }
#pragma unroll
  for (int off = 32; off > 0; off >>= 1) {
    const float ov = __shfl_down(mv, off);
    const int oj = __shfl_down(mj, off);
    if (ov < mv || (ov == mv && oj < mj)) { mv = ov; mj = oj; }
  }
  if (lane == 0) { redV[W] = mv; redJ[W] = mj; }
  __syncthreads();
  if (t == 0) {
    float bm = redV[0]; int bj = redJ[0];
#pragma unroll
    for (int w = 1; w < 4; ++w)
      if (redV[w] < bm) { bm = redV[w]; bj = redJ[w]; }
    partV[b * 4 + chunk] = bm;
    partJ[b * 4 + chunk] = bj;
  }
}

// ---------------------------------------------------------------------------
// Backtrack v3 (R3): 128-row windows, 2 rows decoded per lane. Stage 3 tiles
// x 96 p-rows x 128B = 36KB coalesced into LDS (XOR bank swizzle), decode
// into tab[128][...], serial lane-0 walk up to 128 rows per window.
// ---------------------------------------------------------------------------
__global__ __launch_bounds__(64) void backtrack_kernel(
    const unsigned char* __restrict__ dec, const float* __restrict__ partV,
    const int* __restrict__ partJ, int nch, const float* __restrict__ y_t,
    float* __restrict__ w_vs, float* __restrict__ cost_out) {
  const int b = blockIdx.x;
  const int lane = threadIdx.x;
  __shared__ unsigned int stage[3 * 3072];               // 36 KB
  __shared__ unsigned short tab[BTROWS_][BTQ_ * 4 + 2];  // ~98.8 KB
  __shared__ int st_i, st_j;
  __shared__ int jrow[BTROWS_ + 1];
  const unsigned char* db = dec + (size_t)b * 16 * TSB_;
  const float* yt = y_t + b * M_;
  float* wv = w_vs + b * N_;

  if (lane == 0) {
    float bc = finf(); int bj = 0;
    for (int c = 0; c < nch; ++c) {
      const float v = partV[b * nch + c];
      const int j = partJ[b * nch + c];
      if (v < bc) { bc = v; bj = j; }
    }
    cost_out[b] = bc;
    st_i = N_ - 1;
    st_j = bj;
    wv[N_ - 1] = yt[bj];
  }
  for (;;) {
    __syncthreads();
    const int i = st_i, j = st_j;
    if (i <= 0) break;
    const int qj = j >> 2;
    int qlo = qj - (BTQ_ - 1);
    if (qlo < 0) qlo = 0;
    const int Tbase = qlo >> 6;
    int plo = (i - 127) >> 1;
    if (plo < 0) plo = 0;  // i<=1023 => plo<=448, plo+95<=543=SPAIR_-1

    // --- cooperative coalesced stage: 3 tiles x 96 p-rows x 128B ---
#pragma unroll
    for (int tt = 0; tt < 3; ++tt) {
      int T = Tbase + tt;
      if (T > 15) T = 15;  // duplicate tile 15; never read for that tt
      const uint4* src =
          (const uint4*)(db + (size_t)T * TSB_ + (size_t)plo * 128);
#pragma unroll
      for (int v = 0; v < 12; ++v) {
        const int wb = tt * 12288 + (v * 64 + lane) * 16;
        const int sw = wb ^ (((wb >> 7) & 7) << 4);  // bank swizzle
        *(uint4*)((char*)stage + sw) = src[v * 64 + lane];
      }
    }
    __syncthreads();

    const unsigned char* sb8 = (const unsigned char*)stage;
#pragma unroll
    for (int half = 0; half < 2; ++half) {
      const int r = i - lane - half * 64;
      if (r >= 1) {
        unsigned char wr[BTQ_];
#pragma unroll
        for (int k = 0; k < BTQ_; ++k) {
          const int q = qlo + k;
          const int tt = (q >> 6) - Tbase;
          const int l = q & 63;
          const int s = r + l;
          int idx = tt * 12288 + ((s >> 1) - plo) * 128 + l * 2 + (s & 1);
          idx ^= ((idx >> 7) & 7) << 4;  // matching bank swizzle
          wr[k] = sb8[idx];
        }
        unsigned short run = 0xFFFF;  // stuck sentinel
        const int tr = lane + half * 64;
#pragma unroll
        for (int k = 0; k < BTQ_; ++k) {
          const unsigned int byte = wr[k];
#pragma unroll
          for (int cs = 0; cs < 4; ++cs) {
            const unsigned int code = (byte >> (2 * cs)) & 3u;
            const int c = 4 * k + cs;
            const unsigned short v =
                (code != 2u) ? (unsigned short)((c << 2) | code) : run;
            tab[tr][c] = v;
            run = v;
          }
        }
      }
    }
    __syncthreads();
    if (lane == 0) {
      const int base = qlo << 2;
      int rr = i, cj = j;
      while (rr >= 1 && (i - rr) < BTROWS_) {
        const int l = i - rr;
        const int c = cj - base;
        if (c < 0) break;
        const unsigned short v = tab[l][c];
        if (v == 0xFFFF) { cj = base - 1; break; }
        const int e = v >> 2;
        const int ce = v & 3;
        cj = base + e - (ce == 0 ? 1 : 0);
        --rr;
        jrow[i - rr] = cj;
      }
      st_i = rr;
      st_j = cj;
    }
    __syncthreads();
    const int cnt = i - st_i;
    if (lane < cnt) wv[i - 1 - lane] = yt[jrow[lane + 1]];
    {
      const int l2 = lane + 64;
      if (l2 < cnt) wv[i - 1 - l2] = yt[jrow[l2 + 1]];
    }
  }
}

// ---------------------------------------------------------------------------
extern "C" void kernel_launch(void* const* d_in, const int* in_sizes, int n_in,
                              void* d_out, int out_size, void* d_ws, size_t ws_size,
                              hipStream_t stream) {
  const float* x = (const float*)d_in[0];
  const float* y = (const float*)d_in[1];
  const float* x_t = (const float*)d_in[2];
  const float* y_t = (const float*)d_in[3];

  float* out_cost = (float*)d_out;      // [B_]
  float* out_wts = out_cost + B_;       // [B_][N_]
  float* out_wvs = out_wts + B_ * N_;   // [B_][N_]

  const size_t csBytes = (size_t)B_ * 4 * SROWSP_ * 256 * 4;  // ~72.4 MB
  const size_t decBytes = (size_t)B_ * 16 * TSB_;             // ~17.8 MB
  const size_t x2Bytes = (size_t)B_ * N_ * 4;
  const size_t tailBytes = x2Bytes + 2 * (size_t)B_ * N_ * 4 + B_ * 4 * 8;

  // Overlap (double-Cs) path requires 2*csBytes; fall back to serial if not.
  const int overlap = ws_size >= 2 * csBytes + decBytes + tailBytes;
  const int nCs = overlap ? 2 : 1;

  char* ws = (char*)d_ws;
  float* CsA = (float*)ws;
  float* CsB = overlap ? (float*)(ws + csBytes) : CsA;
  unsigned char* dec = (unsigned char*)(ws + (size_t)nCs * csBytes);
  float* x2 = (float*)(ws + (size_t)nCs * csBytes + decBytes);
  float* carryA = x2 + B_ * N_;
  float* carryB = carryA + B_ * N_;
  float* partV = carryB + B_ * N_;
  int* partJ = (int*)(partV + B_ * 4);

  prep_kernel<<<dim3((B_ * N_) / 256), 256, 0, stream>>>(x, x_t, x2, out_wts);

  float* cbuf[2] = {carryA, carryB};
  if (overlap) {
    // Prologue: gemm chunk 0 -> CsA. Then launch c runs DP(c) + gemm(c+1).
    gemm_kernel<<<dim3(4, N_ / 32, B_), 256, 0, stream>>>(x, y, x2, CsA, 0);
    for (int c = 0; c < 4; ++c) {
      float* csR = (c & 1) ? CsB : CsA;
      float* csW = (c & 1) ? CsA : CsB;
      const int nblk = B_ + (c < 3 ? GEMM_BLKS_ : 0);
      dtw_fused<<<dim3(nblk), 256, 0, stream>>>(
          x, y, x2, csR, csW, (c + 1) * 1024, dec, cbuf[(c + 1) & 1],
          cbuf[c & 1], partV, partJ, c, c > 0 ? 1 : 0);
    }
  } else {
    for (int c = 0; c < 4; ++c) {
      gemm_kernel<<<dim3(4, N_ / 32, B_), 256, 0, stream>>>(x, y, x2, CsA,
                                                            c * 1024);
      dtw_fused<<<dim3(B_), 256, 0, stream>>>(
          x, y, x2, CsA, CsA, 0, dec, cbuf[(c + 1) & 1], cbuf[c & 1], partV,
          partJ, c, c > 0 ? 1 : 0);
    }
  }

  backtrack_kernel<<<dim3(B_), 64, 0, stream>>>(dec, partV, partJ, 4, y_t,
                                                out_wvs, out_cost);
}

// Round 8
// 1009.050 us; speedup vs baseline: 1.2920x; 1.0027x over previous
//
#include <hip/hip_runtime.h>

#define B_ 16
#define N_ 1024
#define M_ 4096
#define D_ 64
#define SROWS_ (N_ + 63)        // 1087 valid skewed steps per tile
#define SROWSP_ (SROWS_ + 17)   // padded stride (prefetch overrun safety)
#define SPAIR_ 544              // step-pairs per tile
#define TSB_ ((size_t)SPAIR_ * 128)  // dec bytes per tile (69632)
#define BTQ_ 96                 // backtrack window quads (384 cells)
#define BTROWS_ 128             // backtrack window rows (2 per lane)
#define GEMM_BLKS_ 2048         // per chunk: 4 tiles x 32 row-groups x 16 b

__device__ __forceinline__ float finf() { return __builtin_inff(); }

__device__ __forceinline__ float wave_shr1(float x) {
  return __int_as_float(__builtin_amdgcn_update_dpp(
      0, __float_as_int(x), 0x138, 0xF, 0xF, false));
}
__device__ __forceinline__ float rdlane(float v, int l) {
  return __int_as_float(__builtin_amdgcn_readlane(__float_as_int(v), l));
}

// ---------------------------------------------------------------------------
__global__ void prep_kernel(const float* __restrict__ x,
                            const float* __restrict__ x_t,
                            float* __restrict__ x2,
                            float* __restrict__ w_ts_out,
                            int* __restrict__ ctrl) {
  int id = blockIdx.x * blockDim.x + threadIdx.x;
  if (ctrl && blockIdx.x == 0 && threadIdx.x < 128)
    ctrl[threadIdx.x] = (threadIdx.x < 64) ? 0 : -1;  // gemmCnt=0, carryProg=-1
  const float4* xr = (const float4*)(x + (size_t)id * D_);
  float s = 0.f;
#pragma unroll
  for (int e = 0; e < D_ / 4; ++e) {
    float4 v = xr[e];
    s += v.x * v.x + v.y * v.y + v.z * v.z + v.w * v.w;
  }
  x2[id] = s;
  w_ts_out[id] = x_t[id];
}

// ---------------------------------------------------------------------------
// gemm body (R2-verified arithmetic, bit-identical C required).
// CsT = destination tile base; jcol0 = global column of this 256-col tile.
// ---------------------------------------------------------------------------
__device__ __forceinline__ void gemm_body(
    const float* __restrict__ x, const float* __restrict__ y,
    const float* __restrict__ x2, float* __restrict__ CsT, int jcol0,
    int b, int ibeg, int t, char* smem) {
  float4* ylds = (float4*)smem;            // [e][col], 64KB
  float4* xlds = (float4*)(smem + 65536);  // [e][row], 8KB
  float* y2lds = (float*)(smem + 73728);   // 1KB

  const int cg = t & 63;
  const int rg = t >> 6;
  {
    const int j = jcol0 + t;
    const float4* yrow = (const float4*)(y + ((size_t)b * M_ + j) * D_);
    float4 yr[16];
#pragma unroll
    for (int e = 0; e < 16; ++e) yr[e] = yrow[e];
    float y2 = 0.f;
#pragma unroll
    for (int e = 0; e < 16; ++e)
      y2 += yr[e].x * yr[e].x + yr[e].y * yr[e].y + yr[e].z * yr[e].z +
            yr[e].w * yr[e].w;
    y2lds[t] = y2;
#pragma unroll
    for (int e = 0; e < 16; ++e) ylds[e * 256 + t] = yr[e];
  }
  if (t < 128) {
    const int row = t >> 2;
    const int part = t & 3;
    const float4* xr = (const float4*)(x + ((size_t)b * N_ + ibeg + row) * D_);
#pragma unroll
    for (int k = 0; k < 4; ++k) {
      const int e = part * 4 + k;
      xlds[e * 32 + row] = xr[e];
    }
  }
  __syncthreads();

  const int r0 = rg * 8;
  float acc[8][4];
#pragma unroll
  for (int r = 0; r < 8; ++r)
#pragma unroll
    for (int c = 0; c < 4; ++c) acc[r][c] = 0.f;

#pragma unroll
  for (int kb = 0; kb < 4; ++kb) {
    float4 yf[4][4];
#pragma unroll
    for (int c = 0; c < 4; ++c)
#pragma unroll
      for (int ee = 0; ee < 4; ++ee)
        yf[c][ee] = ylds[(kb * 4 + ee) * 256 + cg + 64 * c];
#pragma unroll
    for (int r = 0; r < 8; ++r) {
      float4 xv[4];
#pragma unroll
      for (int ee = 0; ee < 4; ++ee)
        xv[ee] = xlds[(kb * 4 + ee) * 32 + r0 + r];
#pragma unroll
      for (int ee = 0; ee < 4; ++ee) {
#pragma unroll
        for (int c = 0; c < 4; ++c) {
          acc[r][c] += xv[ee].x * yf[c][ee].x + xv[ee].y * yf[c][ee].y +
                       xv[ee].z * yf[c][ee].z + xv[ee].w * yf[c][ee].w;
        }
      }
    }
  }

#pragma unroll
  for (int r = 0; r < 8; ++r) {
    const int i = ibeg + r0 + r;
    const float xx = x2[b * N_ + i];
#pragma unroll
    for (int c = 0; c < 4; ++c) {
      const int ct = cg + 64 * c;
      const int l = ct >> 2;
      CsT[(size_t)(i + l) * 256 + ct] = xx + y2lds[ct] - 2.f * acc[r][c];
    }
  }
}

// ---------------------------------------------------------------------------
// Standalone GEMM. nt = tiles-per-batch stride in Cs (4: chunk buffer, 16:
// full buffer); tileOff = global tile offset of tile 0 of this grid.
// ---------------------------------------------------------------------------
__global__ __launch_bounds__(256) void gemm_kernel(
    const float* __restrict__ x, const float* __restrict__ y,
    const float* __restrict__ x2, float* __restrict__ Cs, int chunkBase,
    int nt, int tileOff) {
  __shared__ __align__(16) char smem[74752];
  const int tile = blockIdx.x;
  const int b = blockIdx.z;
  float* CsT =
      Cs + ((size_t)b * nt + tileOff + tile) * SROWSP_ * 256;
  gemm_body(x, y, x2, CsT, chunkBase + tile * 256, b, blockIdx.y * 32,
            threadIdx.x, smem);
}

// ---------------------------------------------------------------------------
// R7 NEW: single-launch fully-pipelined DP. Blocks 0..63 = (b, chunk) DP
// blocks (4 waves each, CU-exclusive via 88KB LDS). Chunk boundaries chained
// via global carry pipe: producer (W3) stores rows every 8 steps, publishes
// progress once per 64 rows (release atomic); consumer (W0 of next chunk)
// polls once per 64-step superblock (acquire + s_sleep) and consumes 64 rows
// per edgeVec load (R4 superblock pattern, only on the global boundary).
// Blocks 64.. = fused gemm for chunks 1..3 (gated by per-(b,chunk) atomic
// counters). Dependency DAG is acyclic; DP holds <=64 CUs so gemm always
// progresses -> no deadlock in any dispatch order.
// ---------------------------------------------------------------------------
__global__ __launch_bounds__(256) void dtw_pipe(
    const float* __restrict__ x, const float* __restrict__ y,
    const float* __restrict__ x2, float* __restrict__ Cs,
    unsigned char* __restrict__ dec, float* __restrict__ carryPipe,
    int* __restrict__ gemmCnt, int* __restrict__ carryProg,
    float* __restrict__ partV, int* __restrict__ partJ) {
  __shared__ __align__(16) char smem[90112];  // 88KB: 1 block/CU
  const int bid = blockIdx.x;
  const int t = threadIdx.x;

  if (bid >= 64) {  // ---- fused gemm, chunks 1..3 ----
    const int gb = bid - 64;
    const int chunk = 1 + (gb >> 11);
    const int g2 = gb & 2047;
    const int b = g2 >> 7;
    const int tile = g2 & 3;
    const int ibeg = ((g2 >> 2) & 31) * 32;
    float* CsT =
        Cs + ((size_t)b * 16 + chunk * 4 + tile) * SROWSP_ * 256;
    gemm_body(x, y, x2, CsT, chunk * 1024 + tile * 256, b, ibeg, t, smem);
    __syncthreads();  // all waves' stores drained (compiler waitcnt)
    if (t == 0) {
      __threadfence();  // agent release: writeback before counter bump
      atomicAdd(&gemmCnt[b * 4 + chunk], 1);
    }
    return;
  }

  // ---- DP block (b, C) ----
  const int b = bid >> 2;
  const int C = bid & 3;
  const int lane = t & 63;
  const int W = t >> 6;

  float(*ring)[1024] = reinterpret_cast<float(*)[1024]>(smem);  // 12KB
  int* prog = reinterpret_cast<int*>(smem + 12288);
  float* redV = reinterpret_cast<float*>(smem + 12352);
  int* redJ = reinterpret_cast<int*>(smem + 12384);
  volatile int* vProg = prog;

  if (t < 3) prog[t] = -1;

  if (C > 0) {  // gemm gate: Cs tiles for this chunk must be complete
    if (t == 0) {
      while (__hip_atomic_load(&gemmCnt[b * 4 + C], __ATOMIC_ACQUIRE,
                               __HIP_MEMORY_SCOPE_AGENT) < 128)
        __builtin_amdgcn_s_sleep(8);
      __threadfence();  // invalidate stale cache before block reads Cs
    }
    __syncthreads();
  } else {
    __syncthreads();
  }

  const float INF = finf();
  const float* loadP = Cs + ((size_t)b * 16 + C * 4 + W) * SROWSP_ * 256;
  const int tileG = C * 4 + W;
  unsigned short* decP =
      (unsigned short*)(dec + (size_t)(b * 16 + tileG) * TSB_) + lane;
  const float* carryIn = carryPipe + ((size_t)b * 3 + (C > 0 ? C - 1 : 0)) * N_;
  float* carryOut = carryPipe + ((size_t)b * 3 + (C < 3 ? C : 0)) * N_;
  int* progIn = &carryProg[b * 4 + (C > 0 ? C - 1 : 0)];
  int* progOut = &carryProg[b * 4 + C];
  const int jbase = tileG * 256 + lane * 4;

  float4 cc0 = ((const float4*)(loadP + 0 * 256))[lane];
  float4 cc1 = ((const float4*)(loadP + 1 * 256))[lane];
  float4 cc2 = ((const float4*)(loadP + 2 * 256))[lane];
  float4 cc3 = ((const float4*)(loadP + 3 * 256))[lane];
  float4 cc4 = ((const float4*)(loadP + 4 * 256))[lane];
  float4 cc5 = ((const float4*)(loadP + 5 * 256))[lane];
  float4 cc6 = ((const float4*)(loadP + 6 * 256))[lane];
  float4 cc7 = ((const float4*)(loadP + 7 * 256))[lane];
  loadP += 8 * 256;

  float edgeVec = INF, lvPrev = INF;
  float up0 = 0.f, up1 = 0.f, up2 = 0.f, up3 = 0.f;
  float dpp1 = INF, dpp2 = INF;
  float fin0 = INF, fin1 = INF, fin2 = INF, fin3 = INF;
  float ebuf[8];

// W>0: intra-block LDS ring, reload every 8 steps (proven R2 structure).
// W==0 && C>0: global carry, superblock consume: poll+reload every 64 steps.
// lvPrev for the superblock path is carried by the DPSTEP chain (R4 insight).
#define BLOCKHEADP()                                                          \
  {                                                                           \
    if (W > 0) {                                                              \
      if (sb < N_) {                                                          \
        const int tgt = sb + 7;                                               \
        while (vProg[W - 1] < tgt) {}                                         \
        asm volatile("" ::: "memory");                                        \
        lvPrev = rdlane(edgeVec, 7);                                          \
        edgeVec = ring[W - 1][(sb + lane) & 1023];                            \
      }                                                                       \
    } else if (C > 0) {                                                       \
      if (((sb & 63) == 0) && sb < N_) {                                      \
        const int tgt = sb + 63;                                              \
        if (lane == 0) {                                                      \
          while (__hip_atomic_load(progIn, __ATOMIC_ACQUIRE,                  \
                                   __HIP_MEMORY_SCOPE_AGENT) < tgt)           \
            __builtin_amdgcn_s_sleep(4);                                      \
        }                                                                     \
        edgeVec = carryIn[(sb + lane) & 1023];                                \
      }                                                                       \
    }                                                                         \
  }

#define DPSTEP(KK, CCV, ROW0, FIN)                                            \
  {                                                                           \
    const float lv = rdlane(edgeVec, eb + (KK));                              \
    const float left = (lane == 0) ? lv : dpp1;                               \
    const float diag = (lane == 0) ? lvPrev : dpp2;                           \
    lvPrev = lv;                                                              \
    float bv0 = fminf(diag, fminf(up0, left));                                \
    unsigned int pk = (diag <= bv0) ? 0u : ((up0 <= bv0) ? 1u : 2u);          \
    if (ROW0) bv0 = (sb + (KK) == lane) ? 0.f : bv0;                          \
    const float D0 = CCV.x + bv0;                                             \
    float bv1 = fminf(up0, fminf(up1, D0));                                   \
    pk |= (up0 <= bv1) ? 0u : ((up1 <= bv1) ? 4u : 8u);                       \
    if (ROW0) bv1 = (sb + (KK) == lane) ? 0.f : bv1;                          \
    const float D1 = CCV.y + bv1;                                             \
    float bv2 = fminf(up1, fminf(up2, D1));                                   \
    pk |= (up1 <= bv2) ? 0u : ((up2 <= bv2) ? 16u : 32u);                     \
    if (ROW0) bv2 = (sb + (KK) == lane) ? 0.f : bv2;                          \
    const float D2 = CCV.z + bv2;                                             \
    float bv3 = fminf(up2, fminf(up3, D2));                                   \
    pk |= (up2 <= bv3) ? 0u : ((up3 <= bv3) ? 64u : 128u);                    \
    if (ROW0) bv3 = (sb + (KK) == lane) ? 0.f : bv3;                          \
    const float D3 = CCV.w + bv3;                                             \
    ebuf[(KK)] = D3;                                                          \
    if ((KK) & 1) {                                                           \
      pk16 |= pk << 8;                                                        \
      decP[((KK) >> 1) * 64] = (unsigned short)pk16;                          \
    } else {                                                                  \
      pk16 = pk;                                                              \
    }                                                                         \
    if (FIN) {                                                                \
      const bool lr = (sb + (KK) == 1023 + lane);                             \
      fin0 = lr ? D0 : fin0; fin1 = lr ? D1 : fin1;                           \
      fin2 = lr ? D2 : fin2; fin3 = lr ? D3 : fin3;                           \
    }                                                                         \
    const float sh = wave_shr1(D3);                                           \
    dpp2 = dpp1; dpp1 = sh;                                                   \
    up0 = D0; up1 = D1; up2 = D2; up3 = D3;                                   \
    CCV = ((const float4*)(loadP + (KK) * 256))[lane];                        \
  }

#define BLOCKENDP()                                                           \
  {                                                                           \
    const int r0 = sb - 63;                                                   \
    if (W < 3) {                                                              \
      if (lane == 63 && r0 > -8 && r0 < N_) {                                 \
        _Pragma("unroll") for (int k = 0; k < 8; ++k) {                       \
          const int r = r0 + k;                                               \
          if ((unsigned)r < (unsigned)N_) ring[W][r] = ebuf[k];               \
        }                                                                     \
        __builtin_amdgcn_s_waitcnt(0xC07F);                                   \
        vProg[W] = r0 + 7;                                                    \
      }                                                                       \
    } else if (C < 3) {                                                       \
      if (lane == 63) {                                                       \
        if (r0 > -8 && r0 < N_) {                                             \
          _Pragma("unroll") for (int k = 0; k < 8; ++k) {                     \
            const int r = r0 + k;                                             \
            if ((unsigned)r < (unsigned)N_) carryOut[r] = ebuf[k];            \
          }                                                                   \
        }                                                                     \
        if ((sb & 63) == 56)                                                  \
          __hip_atomic_store(progOut, sb - 56, __ATOMIC_RELEASE,              \
                             __HIP_MEMORY_SCOPE_AGENT);                       \
      }                                                                       \
    }                                                                         \
    loadP += 8 * 256;                                                         \
    decP += 256;                                                              \
  }

#define STEP8(R0, FN)                                                         \
  DPSTEP(0, cc0, R0, FN) DPSTEP(1, cc1, R0, FN) DPSTEP(2, cc2, R0, FN)        \
  DPSTEP(3, cc3, R0, FN) DPSTEP(4, cc4, R0, FN) DPSTEP(5, cc5, R0, FN)        \
  DPSTEP(6, cc6, R0, FN) DPSTEP(7, cc7, R0, FN)

  int sb = 0;
  for (; sb < 64; sb += 8) {   // prologue: row-0 selects live
    BLOCKHEADP();
    const int eb = (W == 0) ? (sb & 56) : 0;
    unsigned int pk16;
    STEP8(1, 0)
    BLOCKENDP();
  }
  for (; sb < 1016; sb += 8) { // main
    BLOCKHEADP();
    const int eb = (W == 0) ? (sb & 56) : 0;
    unsigned int pk16;
    STEP8(0, 0)
    BLOCKENDP();
  }
  for (; sb < 1088; sb += 8) { // epilogue: fin captures
    BLOCKHEADP();
    const int eb = (W == 0) ? (sb & 56) : 0;
    unsigned int pk16;
    STEP8(0, 1)
    BLOCKENDP();
  }
#undef DPSTEP
#undef STEP8
#undef BLOCKHEADP
#undef BLOCKENDP

  float mv = fin0; int mj = jbase;
  if (fin1 < mv) { mv = fin1; mj = jbase + 1; }
  if (fin2 < mv) { mv = fin2; mj = jbase + 2; }
  if (fin3 < mv) { mv = fin3; mj = jbase + 3; }
#pragma unroll
  for (int off = 32; off > 0; off >>= 1) {
    const float ov = __shfl_down(mv, off);
    const int oj = __shfl_down(mj, off);
    if (ov < mv || (ov == mv && oj < mj)) { mv = ov; mj = oj; }
  }
  if (lane == 0) { redV[W] = mv; redJ[W] = mj; }
  __syncthreads();
  if (t == 0) {
    float bm = redV[0]; int bj = redJ[0];
#pragma unroll
    for (int w = 1; w < 4; ++w)
      if (redV[w] < bm) { bm = redV[w]; bj = redJ[w]; }
    partV[b * 4 + C] = bm;
    partJ[b * 4 + C] = bj;
  }
}

// ---------------------------------------------------------------------------
// R6 fallback: fused DP+next-gemm kernel (verified at 1011 us). Unchanged
// except gemm_body signature adaptation.
// ---------------------------------------------------------------------------
__global__ __launch_bounds__(256) void dtw_fused(
    const float* __restrict__ x, const float* __restrict__ y,
    const float* __restrict__ x2, const float* __restrict__ CsRead,
    float* __restrict__ CsWrite, int nextBase,
    unsigned char* __restrict__ dec, const float* __restrict__ carryIn,
    float* __restrict__ carryOut, float* __restrict__ partV,
    int* __restrict__ partJ, int chunk, int hasCarry) {
  __shared__ __align__(16) char smem[90112];
  const int bid = blockIdx.x;
  const int t = threadIdx.x;

  if (bid >= B_) {  // ---- gemm for chunk+1 ----
    const int gb = bid - B_;
    const int b = gb >> 7;
    const int tile = gb & 3;
    const int ibeg = ((gb >> 2) & 31) * 32;
    float* CsT = CsWrite + ((size_t)b * 4 + tile) * SROWSP_ * 256;
    gemm_body(x, y, x2, CsT, nextBase + tile * 256, b, ibeg, t, smem);
    return;
  }

  float(*ring)[1024] = reinterpret_cast<float(*)[1024]>(smem);
  float* cring = reinterpret_cast<float*>(smem + 12288);
  int* prog = reinterpret_cast<int*>(smem + 16384);
  float* redV = reinterpret_cast<float*>(smem + 16400);
  int* redJ = reinterpret_cast<int*>(smem + 16416);
  volatile int* vProg = prog;

  const int b = bid;
  const int lane = t & 63;
  const int W = t >> 6;

  if (t < 3) prog[t] = -1;
  const float* cIn = carryIn + b * N_;
  if (hasCarry) ((float4*)cring)[t] = ((const float4*)cIn)[t];
  __syncthreads();

  const float INF = finf();
  const float* loadP = CsRead + (size_t)(b * 4 + W) * SROWSP_ * 256;
  const int tileG = chunk * 4 + W;
  unsigned short* decP =
      (unsigned short*)(dec + (size_t)(b * 16 + tileG) * TSB_) + lane;
  float* carryB = carryOut + b * N_;
  const int jbase = tileG * 256 + lane * 4;

  float4 cc0 = ((const float4*)(loadP + 0 * 256))[lane];
  float4 cc1 = ((const float4*)(loadP + 1 * 256))[lane];
  float4 cc2 = ((const float4*)(loadP + 2 * 256))[lane];
  float4 cc3 = ((const float4*)(loadP + 3 * 256))[lane];
  float4 cc4 = ((const float4*)(loadP + 4 * 256))[lane];
  float4 cc5 = ((const float4*)(loadP + 5 * 256))[lane];
  float4 cc6 = ((const float4*)(loadP + 6 * 256))[lane];
  float4 cc7 = ((const float4*)(loadP + 7 * 256))[lane];
  loadP += 8 * 256;

  float edgeVec = INF, lvPrev = INF;
  float up0 = 0.f, up1 = 0.f, up2 = 0.f, up3 = 0.f;
  float dpp1 = INF, dpp2 = INF;
  float fin0 = INF, fin1 = INF, fin2 = INF, fin3 = INF;
  float ebuf[8];

#define BLOCKHEAD()                                                           \
  {                                                                           \
    if (W > 0) {                                                              \
      if (sb < N_) {                                                          \
        const int tgt = sb + 7;                                               \
        while (vProg[W - 1] < tgt) {}                                         \
        asm volatile("" ::: "memory");                                        \
        lvPrev = rdlane(edgeVec, 7);                                          \
        edgeVec = ring[W - 1][(sb + lane) & 1023];                            \
      }                                                                       \
    } else if (hasCarry) {                                                    \
      lvPrev = rdlane(edgeVec, 7);                                            \
      if (sb < N_) edgeVec = cring[(sb + lane) & 1023];                       \
    }                                                                         \
  }

#define DPSTEP(KK, CCV, ROW0, FIN)                                            \
  {                                                                           \
    const float lv = rdlane(edgeVec, (KK));                                   \
    const float left = (lane == 0) ? lv : dpp1;                               \
    const float diag = (lane == 0) ? lvPrev : dpp2;                           \
    lvPrev = lv;                                                              \
    float bv0 = fminf(diag, fminf(up0, left));                                \
    unsigned int pk = (diag <= bv0) ? 0u : ((up0 <= bv0) ? 1u : 2u);          \
    if (ROW0) bv0 = (sb + (KK) == lane) ? 0.f : bv0;                          \
    const float D0 = CCV.x + bv0;                                             \
    float bv1 = fminf(up0, fminf(up1, D0));                                   \
    pk |= (up0 <= bv1) ? 0u : ((up1 <= bv1) ? 4u : 8u);                       \
    if (ROW0) bv1 = (sb + (KK) == lane) ? 0.f : bv1;                          \
    const float D1 = CCV.y + bv1;                                             \
    float bv2 = fminf(up1, fminf(up2, D1));                                   \
    pk |= (up1 <= bv2) ? 0u : ((up2 <= bv2) ? 16u : 32u);                     \
    if (ROW0) bv2 = (sb + (KK) == lane) ? 0.f : bv2;                          \
    const float D2 = CCV.z + bv2;                                             \
    float bv3 = fminf(up2, fminf(up3, D2));                                   \
    pk |= (up2 <= bv3) ? 0u : ((up3 <= bv3) ? 64u : 128u);                    \
    if (ROW0) bv3 = (sb + (KK) == lane) ? 0.f : bv3;                          \
    const float D3 = CCV.w + bv3;                                             \
    ebuf[(KK)] = D3;                                                          \
    if ((KK) & 1) {                                                           \
      pk16 |= pk << 8;                                                        \
      decP[((KK) >> 1) * 64] = (unsigned short)pk16;                          \
    } else {                                                                  \
      pk16 = pk;                                                              \
    }                                                                         \
    if (FIN) {                                                                \
      const bool lr = (sb + (KK) == 1023 + lane);                             \
      fin0 = lr ? D0 : fin0; fin1 = lr ? D1 : fin1;                           \
      fin2 = lr ? D2 : fin2; fin3 = lr ? D3 : fin3;                           \
    }                                                                         \
    const float sh = wave_shr1(D3);                                           \
    dpp2 = dpp1; dpp1 = sh;                                                   \
    up0 = D0; up1 = D1; up2 = D2; up3 = D3;                                   \
    CCV = ((const float4*)(loadP + (KK) * 256))[lane];                        \
  }

#define BLOCKEND()                                                            \
  {                                                                           \
    const int r0 = sb - 63;                                                   \
    if (W < 3) {                                                              \
      if (lane == 63 && r0 > -8 && r0 < N_) {                                 \
        _Pragma("unroll") for (int k = 0; k < 8; ++k) {                       \
          const int r = r0 + k;                                               \
          if ((unsigned)r < (unsigned)N_) ring[W][r] = ebuf[k];               \
        }                                                                     \
        __builtin_amdgcn_s_waitcnt(0xC07F);                                   \
        vProg[W] = r0 + 7;                                                    \
      }                                                                       \
    } else if (chunk < 3) {                                                   \
      if (lane == 63 && r0 > -8 && r0 < N_) {                                 \
        _Pragma("unroll") for (int k = 0; k < 8; ++k) {                       \
          const int r = r0 + k;                                               \
          if ((unsigned)r < (unsigned)N_) carryB[r] = ebuf[k];                \
        }                                                                     \
      }                                                                       \
    }                                                                         \
    loadP += 8 * 256;                                                         \
    decP += 256;                                                              \
  }

#define STEP8(R0, FN)                                                         \
  DPSTEP(0, cc0, R0, FN) DPSTEP(1, cc1, R0, FN) DPSTEP(2, cc2, R0, FN)        \
  DPSTEP(3, cc3, R0, FN) DPSTEP(4, cc4, R0, FN) DPSTEP(5, cc5, R0, FN)        \
  DPSTEP(6, cc6, R0, FN) DPSTEP(7, cc7, R0, FN)

  int sb = 0;
  for (; sb < 64; sb += 8) {
    BLOCKHEAD();
    unsigned int pk16;
    STEP8(1, 0)
    BLOCKEND();
  }
  for (; sb < 1016; sb += 8) {
    BLOCKHEAD();
    unsigned int pk16;
    STEP8(0, 0)
    BLOCKEND();
  }
  for (; sb < 1088; sb += 8) {
    BLOCKHEAD();
    unsigned int pk16;
    STEP8(0, 1)
    BLOCKEND();
  }
#undef DPSTEP
#undef STEP8
#undef BLOCKHEAD
#undef BLOCKEND

  float mv = fin0; int mj = jbase;
  if (fin1 < mv) { mv = fin1; mj = jbase + 1; }
  if (fin2 < mv) { mv = fin2; mj = jbase + 2; }
  if (fin3 < mv) { mv = fin3; mj = jbase + 3; }
#pragma unroll
  for (int off = 32; off > 0; off >>= 1) {
    const float ov = __shfl_down(mv, off);
    const int oj = __shfl_down(mj, off);
    if (ov < mv || (ov == mv && oj < mj)) { mv = ov; mj = oj; }
  }
  if (lane == 0) { redV[W] = mv; redJ[W] = mj; }
  __syncthreads();
  if (t == 0) {
    float bm = redV[0]; int bj = redJ[0];
#pragma unroll
    for (int w = 1; w < 4; ++w)
      if (redV[w] < bm) { bm = redV[w]; bj = redJ[w]; }
    partV[b * 4 + chunk] = bm;
    partJ[b * 4 + chunk] = bj;
  }
}

// ---------------------------------------------------------------------------
// Backtrack v3 (R3): 128-row windows, coalesced LDS stage, serial walk.
// ---------------------------------------------------------------------------
__global__ __launch_bounds__(64) void backtrack_kernel(
    const unsigned char* __restrict__ dec, const float* __restrict__ partV,
    const int* __restrict__ partJ, int nch, const float* __restrict__ y_t,
    float* __restrict__ w_vs, float* __restrict__ cost_out) {
  const int b = blockIdx.x;
  const int lane = threadIdx.x;
  __shared__ unsigned int stage[3 * 3072];               // 36 KB
  __shared__ unsigned short tab[BTROWS_][BTQ_ * 4 + 2];  // ~98.8 KB
  __shared__ int st_i, st_j;
  __shared__ int jrow[BTROWS_ + 1];
  const unsigned char* db = dec + (size_t)b * 16 * TSB_;
  const float* yt = y_t + b * M_;
  float* wv = w_vs + b * N_;

  if (lane == 0) {
    float bc = finf(); int bj = 0;
    for (int c = 0; c < nch; ++c) {
      const float v = partV[b * nch + c];
      const int j = partJ[b * nch + c];
      if (v < bc) { bc = v; bj = j; }
    }
    cost_out[b] = bc;
    st_i = N_ - 1;
    st_j = bj;
    wv[N_ - 1] = yt[bj];
  }
  for (;;) {
    __syncthreads();
    const int i = st_i, j = st_j;
    if (i <= 0) break;
    const int qj = j >> 2;
    int qlo = qj - (BTQ_ - 1);
    if (qlo < 0) qlo = 0;
    const int Tbase = qlo >> 6;
    int plo = (i - 127) >> 1;
    if (plo < 0) plo = 0;

#pragma unroll
    for (int tt = 0; tt < 3; ++tt) {
      int T = Tbase + tt;
      if (T > 15) T = 15;
      const uint4* src =
          (const uint4*)(db + (size_t)T * TSB_ + (size_t)plo * 128);
#pragma unroll
      for (int v = 0; v < 12; ++v) {
        const int wb = tt * 12288 + (v * 64 + lane) * 16;
        const int sw = wb ^ (((wb >> 7) & 7) << 4);
        *(uint4*)((char*)stage + sw) = src[v * 64 + lane];
      }
    }
    __syncthreads();

    const unsigned char* sb8 = (const unsigned char*)stage;
#pragma unroll
    for (int half = 0; half < 2; ++half) {
      const int r = i - lane - half * 64;
      if (r >= 1) {
        unsigned char wr[BTQ_];
#pragma unroll
        for (int k = 0; k < BTQ_; ++k) {
          const int q = qlo + k;
          const int tt = (q >> 6) - Tbase;
          const int l = q & 63;
          const int s = r + l;
          int idx = tt * 12288 + ((s >> 1) - plo) * 128 + l * 2 + (s & 1);
          idx ^= ((idx >> 7) & 7) << 4;
          wr[k] = sb8[idx];
        }
        unsigned short run = 0xFFFF;
        const int tr = lane + half * 64;
#pragma unroll
        for (int k = 0; k < BTQ_; ++k) {
          const unsigned int byte = wr[k];
#pragma unroll
          for (int cs = 0; cs < 4; ++cs) {
            const unsigned int code = (byte >> (2 * cs)) & 3u;
            const int c = 4 * k + cs;
            const unsigned short v =
                (code != 2u) ? (unsigned short)((c << 2) | code) : run;
            tab[tr][c] = v;
            run = v;
          }
        }
      }
    }
    __syncthreads();
    if (lane == 0) {
      const int base = qlo << 2;
      int rr = i, cj = j;
      while (rr >= 1 && (i - rr) < BTROWS_) {
        const int l = i - rr;
        const int c = cj - base;
        if (c < 0) break;
        const unsigned short v = tab[l][c];
        if (v == 0xFFFF) { cj = base - 1; break; }
        const int e = v >> 2;
        const int ce = v & 3;
        cj = base + e - (ce == 0 ? 1 : 0);
        --rr;
        jrow[i - rr] = cj;
      }
      st_i = rr;
      st_j = cj;
    }
    __syncthreads();
    const int cnt = i - st_i;
    if (lane < cnt) wv[i - 1 - lane] = yt[jrow[lane + 1]];
    {
      const int l2 = lane + 64;
      if (l2 < cnt) wv[i - 1 - l2] = yt[jrow[l2 + 1]];
    }
  }
}

// ---------------------------------------------------------------------------
extern "C" void kernel_launch(void* const* d_in, const int* in_sizes, int n_in,
                              void* d_out, int out_size, void* d_ws, size_t ws_size,
                              hipStream_t stream) {
  const float* x = (const float*)d_in[0];
  const float* y = (const float*)d_in[1];
  const float* x_t = (const float*)d_in[2];
  const float* y_t = (const float*)d_in[3];

  float* out_cost = (float*)d_out;      // [B_]
  float* out_wts = out_cost + B_;       // [B_][N_]
  float* out_wvs = out_wts + B_ * N_;   // [B_][N_]

  const size_t csChunk = (size_t)B_ * 4 * SROWSP_ * 256 * 4;   // ~72.4 MB
  const size_t csFull = (size_t)B_ * 16 * SROWSP_ * 256 * 4;   // ~289.4 MB
  const size_t decBytes = (size_t)B_ * 16 * TSB_;              // ~17.8 MB
  const size_t x2Bytes = (size_t)B_ * N_ * 4;
  const size_t pipeTail = x2Bytes + 3 * (size_t)B_ * N_ * 4 + 4096;
  const size_t r6Tail = x2Bytes + 2 * (size_t)B_ * N_ * 4 + B_ * 4 * 8;

  char* ws = (char*)d_ws;

  if (ws_size >= csFull + decBytes + pipeTail) {
    // ---- R7 pipelined path ----
    float* Cs = (float*)ws;
    unsigned char* dec = (unsigned char*)(ws + csFull);
    float* x2 = (float*)(ws + csFull + decBytes);
    float* carryPipe = x2 + B_ * N_;
    float* partV = carryPipe + 3 * B_ * N_;
    int* partJ = (int*)(partV + 64);
    int* ctrl = partJ + 64;  // [0..63]=gemmCnt, [64..127]=carryProg

    prep_kernel<<<dim3((B_ * N_) / 256), 256, 0, stream>>>(x, x_t, x2,
                                                           out_wts, ctrl);
    // chunk-0 gemm prologue (tiles 0..3 of the full 16-tile buffer)
    gemm_kernel<<<dim3(4, N_ / 32, B_), 256, 0, stream>>>(x, y, x2, Cs, 0,
                                                          16, 0);
    dtw_pipe<<<dim3(64 + 3 * GEMM_BLKS_), 256, 0, stream>>>(
        x, y, x2, Cs, dec, carryPipe, ctrl, ctrl + 64, partV, partJ);
    backtrack_kernel<<<dim3(B_), 64, 0, stream>>>(dec, partV, partJ, 4, y_t,
                                                  out_wvs, out_cost);
    return;
  }

  // ---- R6 fallback ----
  const int overlap = ws_size >= 2 * csChunk + decBytes + r6Tail;
  const int nCs = overlap ? 2 : 1;
  float* CsA = (float*)ws;
  float* CsB = overlap ? (float*)(ws + csChunk) : CsA;
  unsigned char* dec = (unsigned char*)(ws + (size_t)nCs * csChunk);
  float* x2 = (float*)(ws + (size_t)nCs * csChunk + decBytes);
  float* carryA = x2 + B_ * N_;
  float* carryB = carryA + B_ * N_;
  float* partV = carryB + B_ * N_;
  int* partJ = (int*)(partV + B_ * 4);

  prep_kernel<<<dim3((B_ * N_) / 256), 256, 0, stream>>>(x, x_t, x2, out_wts,
                                                         nullptr);

  float* cbuf[2] = {carryA, carryB};
  if (overlap) {
    gemm_kernel<<<dim3(4, N_ / 32, B_), 256, 0, stream>>>(x, y, x2, CsA, 0,
                                                          4, 0);
    for (int c = 0; c < 4; ++c) {
      float* csR = (c & 1) ? CsB : CsA;
      float* csW = (c & 1) ? CsA : CsB;
      const int nblk = B_ + (c < 3 ? GEMM_BLKS_ : 0);
      dtw_fused<<<dim3(nblk), 256, 0, stream>>>(
          x, y, x2, csR, csW, (c + 1) * 1024, dec, cbuf[(c + 1) & 1],
          cbuf[c & 1], partV, partJ, c, c > 0 ? 1 : 0);
    }
  } else {
    for (int c = 0; c < 4; ++c) {
      gemm_kernel<<<dim3(4, N_ / 32, B_), 256, 0, stream>>>(x, y, x2, CsA,
                                                            c * 1024, 4, 0);
      dtw_fused<<<dim3(B_), 256, 0, stream>>>(
          x, y, x2, CsA, CsA, 0, dec, cbuf[(c + 1) & 1], cbuf[c & 1], partV,
          partJ, c, c > 0 ? 1 : 0);
    }
  }

  backtrack_kernel<<<dim3(B_), 64, 0, stream>>>(dec, partV, partJ, 4, y_t,
                                                out_wvs, out_cost);
}